// Round 8
// baseline (163861.694 us; speedup 1.0000x reference)
//
#include <hip/hip_runtime.h>
#include <hip/hip_fp16.h>

typedef unsigned short u16;
typedef unsigned int u32;
typedef signed char i8;

#define E 2048
#define T_STEPS 512
#define NB 256   // blocks = CUs; weights partitioned across all register files
#define NT 1024  // 16 waves/block
#define EPB 8    // elements per block
#define WPB 16

// ---------------- helpers ----------------
__device__ __forceinline__ u32 packh2(float a, float b) {
    return (u32)__half_as_ushort(__float2half_rn(a)) |
           ((u32)__half_as_ushort(__float2half_rn(b)) << 16);
}
__device__ __forceinline__ float hlo(u32 u) {
    return __half2float(__ushort_as_half((u16)(u & 0xffffu)));
}
__device__ __forceinline__ float hhi(u32 u) {
    return __half2float(__ushort_as_half((u16)(u >> 16)));
}
__device__ __forceinline__ float4 i8x4_to_f4(u32 v) {
    return make_float4((float)(i8)(v & 0xff), (float)(i8)((v >> 8) & 0xff),
                       (float)(i8)((v >> 16) & 0xff), (float)(i8)((v >> 24) & 0xff));
}
__device__ __forceinline__ float dot4(float4 a, float4 b, float acc) {
    acc = fmaf(a.x, b.x, acc);
    acc = fmaf(a.y, b.y, acc);
    acc = fmaf(a.z, b.z, acc);
    acc = fmaf(a.w, b.w, acc);
    return acc;
}
__device__ __forceinline__ float wred(float t) {
#pragma unroll
    for (int off = 32; off > 0; off >>= 1) t += __shfl_xor(t, off);
    return t;
}
__device__ __forceinline__ float sigm(float v) { return 1.f / (1.f + expf(-v)); }

// ---------------- prep kernels ----------------

__global__ __launch_bounds__(256) void k_cvt_f16(const float* __restrict__ in,
                                                 u16* __restrict__ out, int n8) {
    int i = blockIdx.x * blockDim.x + threadIdx.x;
    if (i >= n8) return;
    const float4* p = (const float4*)in + (size_t)i * 2;
    float4 a = p[0], b = p[1];
    uint4 r;
    r.x = packh2(a.x, a.y);
    r.y = packh2(a.z, a.w);
    r.z = packh2(b.x, b.y);
    r.w = packh2(b.z, b.w);
    ((uint4*)out)[i] = r;
}

// per-row int8 quantization of a (4E x E) matrix: one wave per row
__global__ __launch_bounds__(64) void k_quant(const float* __restrict__ in,
                                              i8* __restrict__ q,
                                              float* __restrict__ scales) {
    const int r = blockIdx.x;
    const int l = threadIdx.x;
    const float* row = in + (size_t)r * E;
    float4 v[8];
    float m = 0.f;
#pragma unroll
    for (int u = 0; u < 8; ++u) {
        v[u] = *(const float4*)(row + u * 256 + l * 4);
        m = fmaxf(m, fmaxf(fmaxf(fabsf(v[u].x), fabsf(v[u].y)),
                           fmaxf(fabsf(v[u].z), fabsf(v[u].w))));
    }
#pragma unroll
    for (int off = 32; off > 0; off >>= 1) m = fmaxf(m, __shfl_xor(m, off));
    const float scale = fmaxf(m, 1e-30f) / 127.f;
    const float inv = 127.f / fmaxf(m, 1e-30f);
    i8* qr = q + (size_t)r * E;
#pragma unroll
    for (int u = 0; u < 8; ++u) {
        int a0 = (int)rintf(v[u].x * inv);
        int a1 = (int)rintf(v[u].y * inv);
        int a2 = (int)rintf(v[u].z * inv);
        int a3 = (int)rintf(v[u].w * inv);
        u32 pk = ((u32)(a0 & 0xff)) | ((u32)(a1 & 0xff) << 8) |
                 ((u32)(a2 & 0xff) << 16) | ((u32)(a3 & 0xff) << 24);
        *(u32*)(qr + u * 256 + l * 4) = pk;
    }
    if (l == 0) scales[r] = scale;
}

__global__ void k_bias(const float* __restrict__ bih0, const float* __restrict__ bhh0,
                       const float* __restrict__ bih1, const float* __restrict__ bhh1,
                       float* __restrict__ bias0, float* __restrict__ bias1) {
    int r = blockIdx.x * blockDim.x + threadIdx.x;
    if (r >= 4 * E) return;
    bias0[r] = bih0[r] + bhh0[r];
    bias1[r] = bih1[r] + bhh1[r];
}

// h0/h1 slot0 = lat, barrier zeroed (every call -> deterministic)
__global__ void k_init(const float* __restrict__ lat, float* __restrict__ h0buf,
                       float* __restrict__ h1buf, u32* __restrict__ bar) {
    int i = blockIdx.x * blockDim.x + threadIdx.x;
    if (i < 512) bar[i] = 0;
    if (i >= E) return;
    float v = lat[i];
    h0buf[i] = v;
    h1buf[i] = v;
}

// ---------------- grid barrier (two-level, sense via monotonic gen) ----------------
__device__ __forceinline__ void gsync(u32* bar, int b) {
    __syncthreads();
    if (threadIdx.x == 0) {
        __threadfence();
        u32* gen = bar + 272;
        const u32 g = __hip_atomic_load(gen, __ATOMIC_RELAXED, __HIP_MEMORY_SCOPE_AGENT);
        const int grp = b >> 4;
        if (__hip_atomic_fetch_add(bar + grp * 16, 1u, __ATOMIC_ACQ_REL,
                                   __HIP_MEMORY_SCOPE_AGENT) == 15u) {
            __hip_atomic_store(bar + grp * 16, 0u, __ATOMIC_RELAXED,
                               __HIP_MEMORY_SCOPE_AGENT);
            if (__hip_atomic_fetch_add(bar + 256, 1u, __ATOMIC_ACQ_REL,
                                       __HIP_MEMORY_SCOPE_AGENT) == 15u) {
                __hip_atomic_store(bar + 256, 0u, __ATOMIC_RELAXED,
                                   __HIP_MEMORY_SCOPE_AGENT);
                __hip_atomic_store(gen, g + 1u, __ATOMIC_RELEASE,
                                   __HIP_MEMORY_SCOPE_AGENT);
            }
        }
        int tmo = 0;
        while (__hip_atomic_load(gen, __ATOMIC_ACQUIRE, __HIP_MEMORY_SCOPE_AGENT) == g) {
            __builtin_amdgcn_s_sleep(2);
            if (++tmo > (1 << 22)) break;  // safety valve: wrong-not-hung on bug
        }
    }
    __syncthreads();
    __threadfence();
}

// ---------------- persistent kernel: all 511 steps, weights in VGPRs ----------------
__global__ __launch_bounds__(NT, 4) void k_persist(
    const u32* __restrict__ Qhh0, const float* __restrict__ sHH0,
    const u32* __restrict__ Qih1, const float* __restrict__ sIH1,
    const u32* __restrict__ Qhh1, const float* __restrict__ sHH1,
    const u32* __restrict__ Wih0h, const u32* __restrict__ Wouth,
    const float* __restrict__ bias0, const float* __restrict__ bias1,
    const float* __restrict__ bout,
    float* __restrict__ h0buf, float* __restrict__ h1buf,
    float* __restrict__ xbuf, float* __restrict__ out, u32* __restrict__ bar) {
    const int b = blockIdx.x;
    const int tid = threadIdx.x;
    const int w = tid >> 6, l = tid & 63;

    __shared__ float h0s[E];
    __shared__ float h1s[E];
    __shared__ float xs[128];
    __shared__ float gl[32];
    __shared__ float red[WPB];
    __shared__ float c0s[EPB], c1s[EPB];

    // ---- one-time: stage this wave's weight rows into registers ----
    // pair p = w*2+k -> gate q = p>>3, elem e = b*8 + (p&7), row = q*E+e
    int rows[2];
    rows[0] = ((w * 2) >> 3) * E + b * EPB + ((w * 2) & 7);
    rows[1] = ((w * 2 + 1) >> 3) * E + b * EPB + ((w * 2 + 1) & 7);
    u32 wH0[2][8], wI1[2][8], wH1[2][8], wI0[2];
    float sH0r[2], sI1r[2], sH1r[2];
#pragma unroll
    for (int k = 0; k < 2; ++k) {
        const size_t rb = (size_t)rows[k] * 512;
#pragma unroll
        for (int j = 0; j < 8; ++j) {
            wH0[k][j] = Qhh0[rb + j * 64 + l];
            wI1[k][j] = Qih1[rb + j * 64 + l];
            wH1[k][j] = Qhh1[rb + j * 64 + l];
        }
        wI0[k] = Wih0h[(size_t)rows[k] * 64 + l];
        sH0r[k] = sHH0[rows[k]];
        sI1r[k] = sIH1[rows[k]];
        sH1r[k] = sHH1[rows[k]];
    }
    u32 wX = 0;
    if (b < 128) wX = Wouth[(size_t)b * 1024 + tid];
    if (tid < EPB) { c0s[tid] = 0.f; c1s[tid] = 0.f; }

    for (int s = 1; s <= T_STEPS; ++s) {
        const int pp = (s - 1) & 1, cp = s & 1;

        // ---- phase X: x(s) = Wout @ h1(s-1) + bout  ( == out[s-1] ) ----
        if (b < 128) {
            const float* h1p = h1buf + pp * E;
            float2 hv = *(const float2*)(h1p + 2 * tid);
            float p = hlo(wX) * hv.x + hhi(wX) * hv.y;
            p = wred(p);
            if (l == 0) red[w] = p;
            __syncthreads();
            if (tid == 0) {
                float sum = bout[b];
#pragma unroll
                for (int i = 0; i < WPB; ++i) sum += red[i];
                xbuf[b] = sum;
                out[(size_t)(s - 1) * 128 + b] = sum;
            }
        }
        if (s == T_STEPS) break;
        gsync(bar, b);

        // ---- stage A inputs: h0(s-1), x(s) ----
        {
            const float* h0p = h0buf + pp * E;
            h0s[tid] = h0p[tid];
            h0s[tid + 1024] = h0p[tid + 1024];
            if (tid < 128) xs[tid] = xbuf[tid];
        }
        __syncthreads();
        // ---- phase A: layer 0 ----
#pragma unroll
        for (int k = 0; k < 2; ++k) {
            float acc = 0.f;
#pragma unroll
            for (int j = 0; j < 8; ++j) {
                float4 hv = *(const float4*)&h0s[4 * (j * 64 + l)];
                acc = dot4(i8x4_to_f4(wH0[k][j]), hv, acc);
            }
            float t = fmaf(acc, sH0r[k],
                           hlo(wI0[k]) * xs[2 * l] + hhi(wI0[k]) * xs[2 * l + 1]);
            t = wred(t);
            if (l == 0) gl[w * 2 + k] = t;
        }
        __syncthreads();
        if (tid < EPB) {
            const int e = b * EPB + tid;
            float gi = gl[tid] + bias0[e];
            float gf = gl[8 + tid] + bias0[E + e];
            float gg = gl[16 + tid] + bias0[2 * E + e];
            float go = gl[24 + tid] + bias0[3 * E + e];
            float cn = fmaf(sigm(gf), c0s[tid], sigm(gi) * tanhf(gg));
            c0s[tid] = cn;
            h0buf[cp * E + e] = sigm(go) * tanhf(cn);
        }
        gsync(bar, b);

        // ---- stage B inputs: h0(s), h1(s-1) ----
        {
            const float* h0c = h0buf + cp * E;
            const float* h1p = h1buf + pp * E;
            h0s[tid] = h0c[tid];
            h0s[tid + 1024] = h0c[tid + 1024];
            h1s[tid] = h1p[tid];
            h1s[tid + 1024] = h1p[tid + 1024];
        }
        __syncthreads();
        // ---- phase B: layer 1 ----
#pragma unroll
        for (int k = 0; k < 2; ++k) {
            float accA = 0.f, accB = 0.f;
#pragma unroll
            for (int j = 0; j < 8; ++j) {
                float4 av = *(const float4*)&h0s[4 * (j * 64 + l)];
                float4 bv = *(const float4*)&h1s[4 * (j * 64 + l)];
                accA = dot4(i8x4_to_f4(wI1[k][j]), av, accA);
                accB = dot4(i8x4_to_f4(wH1[k][j]), bv, accB);
            }
            float t = accA * sI1r[k] + accB * sH1r[k];
            t = wred(t);
            if (l == 0) gl[w * 2 + k] = t;
        }
        __syncthreads();
        if (tid < EPB) {
            const int e = b * EPB + tid;
            float gi = gl[tid] + bias1[e];
            float gf = gl[8 + tid] + bias1[E + e];
            float gg = gl[16 + tid] + bias1[2 * E + e];
            float go = gl[24 + tid] + bias1[3 * E + e];
            float cn = fmaf(sigm(gf), c1s[tid], sigm(gi) * tanhf(gg));
            c1s[tid] = cn;
            h1buf[cp * E + e] = sigm(go) * tanhf(cn);
        }
        gsync(bar, b);
    }
}

extern "C" void kernel_launch(void* const* d_in, const int* in_sizes, int n_in,
                              void* d_out, int out_size, void* d_ws, size_t ws_size,
                              hipStream_t stream) {
    const float* lat = (const float*)d_in[0];
    const float* wih0 = (const float*)d_in[1];
    const float* whh0 = (const float*)d_in[2];
    const float* bih0 = (const float*)d_in[3];
    const float* bhh0 = (const float*)d_in[4];
    const float* wih1 = (const float*)d_in[5];
    const float* whh1 = (const float*)d_in[6];
    const float* bih1 = (const float*)d_in[7];
    const float* bhh1 = (const float*)d_in[8];
    const float* wout = (const float*)d_in[9];
    const float* bout = (const float*)d_in[10];

    const size_t QB = (size_t)4 * E * E;  // 16.78 MB per int8 matrix
    char* p = (char*)d_ws;
    i8* Qhh0 = (i8*)p;  p += QB;
    i8* Qih1 = (i8*)p;  p += QB;
    i8* Qhh1 = (i8*)p;  p += QB;
    float* sHH0 = (float*)p; p += (size_t)4 * E * 4;
    float* sIH1 = (float*)p; p += (size_t)4 * E * 4;
    float* sHH1 = (float*)p; p += (size_t)4 * E * 4;
    u16* Wih0h = (u16*)p; p += (size_t)4 * E * 128 * 2;
    u16* Wouth = (u16*)p; p += (size_t)128 * E * 2;
    float* bias0 = (float*)p; p += (size_t)4 * E * 4;
    float* bias1 = (float*)p; p += (size_t)4 * E * 4;
    float* h0buf = (float*)p; p += (size_t)2 * E * 4;
    float* h1buf = (float*)p; p += (size_t)2 * E * 4;
    float* xbuf = (float*)p;  p += 512;
    u32* bar = (u32*)p;       p += 512 * 4;

    k_quant<<<4 * E, 64, 0, stream>>>(whh0, Qhh0, sHH0);
    k_quant<<<4 * E, 64, 0, stream>>>(wih1, Qih1, sIH1);
    k_quant<<<4 * E, 64, 0, stream>>>(whh1, Qhh1, sHH1);
    const int n8i = 4 * E * 128 / 8;
    k_cvt_f16<<<(n8i + 255) / 256, 256, 0, stream>>>(wih0, Wih0h, n8i);
    const int n8o = 128 * E / 8;
    k_cvt_f16<<<(n8o + 255) / 256, 256, 0, stream>>>(wout, Wouth, n8o);
    k_bias<<<(4 * E + 255) / 256, 256, 0, stream>>>(bih0, bhh0, bih1, bhh1, bias0, bias1);
    k_init<<<(E + 255) / 256, 256, 0, stream>>>(lat, h0buf, h1buf, bar);

    k_persist<<<NB, NT, 0, stream>>>((const u32*)Qhh0, sHH0, (const u32*)Qih1, sIH1,
                                     (const u32*)Qhh1, sHH1, (const u32*)Wih0h,
                                     (const u32*)Wouth, bias0, bias1, bout, h0buf,
                                     h1buf, xbuf, (float*)d_out, bar);
}

// Round 9
// 43743.832 us; speedup vs baseline: 3.7459x; 3.7459x over previous
//
#include <hip/hip_runtime.h>
#include <hip/hip_fp16.h>

typedef unsigned short u16;
typedef unsigned int u32;
typedef unsigned long long u64;
typedef signed char i8;

#define E 2048
#define T_STEPS 512
#define NB 256
#define NT 1024

// ---------------- helpers ----------------
__device__ __forceinline__ float4 i8x4_to_f4(u32 v) {
    return make_float4((float)(i8)(v & 0xff), (float)(i8)((v >> 8) & 0xff),
                       (float)(i8)((v >> 16) & 0xff), (float)(i8)((v >> 24) & 0xff));
}
__device__ __forceinline__ float dot4(float4 a, float4 b, float acc) {
    acc = fmaf(a.x, b.x, acc);
    acc = fmaf(a.y, b.y, acc);
    acc = fmaf(a.z, b.z, acc);
    acc = fmaf(a.w, b.w, acc);
    return acc;
}
__device__ __forceinline__ float wred(float t) {
#pragma unroll
    for (int off = 32; off > 0; off >>= 1) t += __shfl_xor(t, off);
    return t;
}
__device__ __forceinline__ float sigm(float v) { return 1.f / (1.f + expf(-v)); }

__device__ __forceinline__ u64 ald64(const u64* p) {
    return __hip_atomic_load(p, __ATOMIC_RELAXED, __HIP_MEMORY_SCOPE_AGENT);
}
__device__ __forceinline__ void astf(float* p, float v) {
    __hip_atomic_store((u32*)p, __float_as_uint(v), __ATOMIC_RELAXED,
                       __HIP_MEMORY_SCOPE_AGENT);
}

// ---------------- prep kernels ----------------

// W_comb[r][c] = sum_k W_ih0[r][k] * W_out[k][c]  (fp32 out; 8192 x 2048)
__global__ __launch_bounds__(256) void k_wcomb(const float* __restrict__ wih0,
                                               const float* __restrict__ wout,
                                               float* __restrict__ wc) {
    __shared__ float a[8 * 128];
    int r0 = blockIdx.y * 8;
    int c = blockIdx.x * 256 + threadIdx.x;
    for (int i = threadIdx.x; i < 8 * 128; i += 256) a[i] = wih0[r0 * 128 + i];
    __syncthreads();
    float acc[8] = {0.f, 0.f, 0.f, 0.f, 0.f, 0.f, 0.f, 0.f};
    for (int k = 0; k < 128; ++k) {
        float b = wout[k * E + c];
#pragma unroll
        for (int j = 0; j < 8; ++j) acc[j] = fmaf(a[j * 128 + k], b, acc[j]);
    }
#pragma unroll
    for (int j = 0; j < 8; ++j) wc[(size_t)(r0 + j) * E + c] = acc[j];
}

// per-row int8 quantization of a (4E x E) matrix: one wave per row
__global__ __launch_bounds__(64) void k_quant(const float* __restrict__ in,
                                              i8* __restrict__ q,
                                              float* __restrict__ scales) {
    const int r = blockIdx.x;
    const int l = threadIdx.x;
    const float* row = in + (size_t)r * E;
    float4 v[8];
    float m = 0.f;
#pragma unroll
    for (int u = 0; u < 8; ++u) {
        v[u] = *(const float4*)(row + u * 256 + l * 4);
        m = fmaxf(m, fmaxf(fmaxf(fabsf(v[u].x), fabsf(v[u].y)),
                           fmaxf(fabsf(v[u].z), fabsf(v[u].w))));
    }
#pragma unroll
    for (int off = 32; off > 0; off >>= 1) m = fmaxf(m, __shfl_xor(m, off));
    const float scale = fmaxf(m, 1e-30f) / 127.f;
    const float inv = 127.f / fmaxf(m, 1e-30f);
    i8* qr = q + (size_t)r * E;
#pragma unroll
    for (int u = 0; u < 8; ++u) {
        int a0 = (int)rintf(v[u].x * inv);
        int a1 = (int)rintf(v[u].y * inv);
        int a2 = (int)rintf(v[u].z * inv);
        int a3 = (int)rintf(v[u].w * inv);
        u32 pk = ((u32)(a0 & 0xff)) | ((u32)(a1 & 0xff) << 8) |
                 ((u32)(a2 & 0xff) << 16) | ((u32)(a3 & 0xff) << 24);
        *(u32*)(qr + u * 256 + l * 4) = pk;
    }
    if (l == 0) scales[r] = scale;
}

// W_outT[e][d] = W_out[d][e]
__global__ void k_transpose_wout(const float* __restrict__ wout, float* __restrict__ woutT) {
    int o = blockIdx.x * blockDim.x + threadIdx.x;
    if (o >= E * 128) return;
    int e = o >> 7, d = o & 127;
    woutT[o] = wout[d * E + e];
}

// bcomb[r] = b_ih0[r]+b_hh0[r]+dot(W_ih0[r],b_out);  bias1[r] = b_ih1[r]+b_hh1[r]
__global__ void k_bcomb(const float* __restrict__ wih0, const float* __restrict__ bout,
                        const float* __restrict__ bih0, const float* __restrict__ bhh0,
                        const float* __restrict__ bih1, const float* __restrict__ bhh1,
                        float* __restrict__ bcomb, float* __restrict__ bias1) {
    int r = blockIdx.x * blockDim.x + threadIdx.x;
    if (r >= 4 * E) return;
    float acc = bih0[r] + bhh0[r];
    const float* w = wih0 + (size_t)r * 128;
#pragma unroll 8
    for (int k = 0; k < 128; ++k) acc = fmaf(w[k], bout[k], acc);
    bcomb[r] = acc;
    bias1[r] = bih1[r] + bhh1[r];
}

// h1hist[0] = lat, h0buf slot0 = lat, zero barrier
__global__ void k_init(const float* __restrict__ lat, float* __restrict__ h0buf,
                       float* __restrict__ h1hist, u32* __restrict__ bar) {
    int i = blockIdx.x * blockDim.x + threadIdx.x;
    if (i < 1056) bar[i] = 0;
    if (i >= E) return;
    float v = lat[i];
    h0buf[i] = v;
    h1hist[i] = v;
}

// ---------------- grid barrier: 64 leaves x 4 blocks, monotone counts ----------------
__device__ __forceinline__ void gbar(u32* bar, int b, u32 bcount) {
    __syncthreads();  // drains this block's stores (vmcnt(0) before s_barrier)
    if (b == 0) {
        if (threadIdx.x == 0)
            __hip_atomic_fetch_add(bar + (b & 63) * 16, 1u, __ATOMIC_RELEASE,
                                   __HIP_MEMORY_SCOPE_AGENT);
        if (threadIdx.x < 64) {
            u32* leaf = bar + threadIdx.x * 16;
            int tmo = 0;
            while (__hip_atomic_load(leaf, __ATOMIC_RELAXED,
                                     __HIP_MEMORY_SCOPE_AGENT) < 4u * bcount) {
                __builtin_amdgcn_s_sleep(1);
                if (++tmo > (1 << 19)) break;  // safety valve
            }
        }
        if (threadIdx.x == 0)
            __hip_atomic_store(bar + 1024, bcount, __ATOMIC_RELEASE,
                               __HIP_MEMORY_SCOPE_AGENT);
    } else {
        if (threadIdx.x == 0) {
            __hip_atomic_fetch_add(bar + (b & 63) * 16, 1u, __ATOMIC_RELEASE,
                                   __HIP_MEMORY_SCOPE_AGENT);
            int tmo = 0;
            while (__hip_atomic_load(bar + 1024, __ATOMIC_RELAXED,
                                     __HIP_MEMORY_SCOPE_AGENT) < bcount) {
                __builtin_amdgcn_s_sleep(8);
                if (++tmo > (1 << 17)) break;  // safety valve
            }
        }
    }
    __syncthreads();
}

// ---------------- persistent kernel: 511 steps, 2 barriers/step, weights in VGPRs ----
__global__ __launch_bounds__(NT, 4) void k_persist(
    const u32* __restrict__ Qc, const float* __restrict__ sC,
    const u32* __restrict__ Qh0, const float* __restrict__ sH0,
    const u32* __restrict__ Qi1, const float* __restrict__ sI1,
    const u32* __restrict__ Qh1, const float* __restrict__ sH1,
    const float* __restrict__ bcomb, const float* __restrict__ bias1,
    float* __restrict__ h0buf, float* __restrict__ h1hist, u32* __restrict__ bar) {
    const int b = blockIdx.x;
    const int tid = threadIdx.x;
    const int w = tid >> 6, l = tid & 63;

    __shared__ float h1s[E], h0s[E];
    __shared__ float gl[32];
    __shared__ float c0s[8], c1s[8];

    // rows for this wave: r = w*2+k in [0,32); gate q=r>>3, elem i=r&7; global row q*E+b*8+i
    int rows[2];
    rows[0] = ((w * 2) >> 3) * E + b * 8 + ((w * 2) & 7);
    rows[1] = ((w * 2 + 1) >> 3) * E + b * 8 + ((w * 2 + 1) & 7);
    u32 wC[2][8], wH0[2][8], wI1[2][8], wH1[2][8];
    float sCr[2], sH0r[2], sI1r[2], sH1r[2];
#pragma unroll
    for (int k = 0; k < 2; ++k) {
        const size_t rb = (size_t)rows[k] * 512;  // u32 units
#pragma unroll
        for (int j = 0; j < 8; ++j) {
            wC[k][j] = Qc[rb + j * 64 + l];
            wH0[k][j] = Qh0[rb + j * 64 + l];
            wI1[k][j] = Qi1[rb + j * 64 + l];
            wH1[k][j] = Qh1[rb + j * 64 + l];
        }
        sCr[k] = sC[rows[k]];
        sH0r[k] = sH0[rows[k]];
        sI1r[k] = sI1[rows[k]];
        sH1r[k] = sH1[rows[k]];
    }
    if (tid < 8) { c0s[tid] = 0.f; c1s[tid] = 0.f; }

    u32 bcount = 0;
    for (int s = 1; s < T_STEPS; ++s) {
        const int pp = (s - 1) & 1, cp = s & 1;

        // stage h1(s-1), h0(s-1) via IC-coherent loads
        ((u64*)h1s)[tid] = ald64((const u64*)(h1hist + (size_t)(s - 1) * E) + tid);
        ((u64*)h0s)[tid] = ald64((const u64*)(h0buf + pp * E) + tid);
        __syncthreads();

        // phase A: gates0 = Wcomb@h1(s-1) + Whh0@h0(s-1)
#pragma unroll
        for (int k = 0; k < 2; ++k) {
            float aC = 0.f, aH = 0.f;
#pragma unroll
            for (int j = 0; j < 8; ++j) {
                float4 v1 = *(const float4*)&h1s[4 * (j * 64 + l)];
                float4 v0 = *(const float4*)&h0s[4 * (j * 64 + l)];
                aC = dot4(i8x4_to_f4(wC[k][j]), v1, aC);
                aH = dot4(i8x4_to_f4(wH0[k][j]), v0, aH);
            }
            float t = wred(aC * sCr[k] + aH * sH0r[k]);
            if (l == 0) gl[w * 2 + k] = t;
        }
        __syncthreads();
        if (tid < 8) {
            const int e = b * 8 + tid;
            float gi = gl[tid] + bcomb[e];
            float gf = gl[8 + tid] + bcomb[E + e];
            float gg = gl[16 + tid] + bcomb[2 * E + e];
            float go = gl[24 + tid] + bcomb[3 * E + e];
            float cn = fmaf(sigm(gf), c0s[tid], sigm(gi) * tanhf(gg));
            c0s[tid] = cn;
            astf(&h0buf[cp * E + e], sigm(go) * tanhf(cn));
        }
        ++bcount;
        gbar(bar, b, bcount);

        // stage h0(s)
        ((u64*)h0s)[tid] = ald64((const u64*)(h0buf + cp * E) + tid);
        __syncthreads();

        // phase B: gates1 = Qih1@h0(s) + Qhh1@h1(s-1)   (h1s still staged)
#pragma unroll
        for (int k = 0; k < 2; ++k) {
            float aI = 0.f, aH = 0.f;
#pragma unroll
            for (int j = 0; j < 8; ++j) {
                float4 v0 = *(const float4*)&h0s[4 * (j * 64 + l)];
                float4 v1 = *(const float4*)&h1s[4 * (j * 64 + l)];
                aI = dot4(i8x4_to_f4(wI1[k][j]), v0, aI);
                aH = dot4(i8x4_to_f4(wH1[k][j]), v1, aH);
            }
            float t = wred(aI * sI1r[k] + aH * sH1r[k]);
            if (l == 0) gl[w * 2 + k] = t;
        }
        __syncthreads();
        if (tid < 8) {
            const int e = b * 8 + tid;
            float gi = gl[tid] + bias1[e];
            float gf = gl[8 + tid] + bias1[E + e];
            float gg = gl[16 + tid] + bias1[2 * E + e];
            float go = gl[24 + tid] + bias1[3 * E + e];
            float cn = fmaf(sigm(gf), c1s[tid], sigm(gi) * tanhf(gg));
            c1s[tid] = cn;
            astf(&h1hist[(size_t)s * E + e], sigm(go) * tanhf(cn));
        }
        ++bcount;
        gbar(bar, b, bcount);
    }
}

// ---------------- final output GEMM: out[t] = Wout @ h1hist[t] + bout ----------------
__global__ __launch_bounds__(128) void k_out(const float* __restrict__ woutT,
                                             const float* __restrict__ hist,
                                             const float* __restrict__ bout,
                                             float* __restrict__ out) {
    __shared__ float h[E];
    int t = blockIdx.x, d = threadIdx.x;
    for (int i = d; i < E; i += 128) h[i] = hist[(size_t)t * E + i];
    __syncthreads();
    float acc0 = bout[d], acc1 = 0.f;
#pragma unroll 4
    for (int k = 0; k < E; k += 2) {
        acc0 = fmaf(woutT[k * 128 + d], h[k], acc0);
        acc1 = fmaf(woutT[(k + 1) * 128 + d], h[k + 1], acc1);
    }
    out[t * 128 + d] = acc0 + acc1;
}

extern "C" void kernel_launch(void* const* d_in, const int* in_sizes, int n_in,
                              void* d_out, int out_size, void* d_ws, size_t ws_size,
                              hipStream_t stream) {
    const float* lat = (const float*)d_in[0];
    const float* wih0 = (const float*)d_in[1];
    const float* whh0 = (const float*)d_in[2];
    const float* bih0 = (const float*)d_in[3];
    const float* bhh0 = (const float*)d_in[4];
    const float* wih1 = (const float*)d_in[5];
    const float* whh1 = (const float*)d_in[6];
    const float* bih1 = (const float*)d_in[7];
    const float* bhh1 = (const float*)d_in[8];
    const float* wout = (const float*)d_in[9];
    const float* bout = (const float*)d_in[10];

    const size_t QB = (size_t)4 * E * E;  // 16.78 MB int8
    char* p = (char*)d_ws;
    i8* Qc = (i8*)p;   p += QB;
    i8* Qh0 = (i8*)p;  p += QB;
    i8* Qi1 = (i8*)p;  p += QB;
    i8* Qh1 = (i8*)p;  p += QB;
    float* sC = (float*)p;  p += (size_t)4 * E * 4;
    float* sH0 = (float*)p; p += (size_t)4 * E * 4;
    float* sI1 = (float*)p; p += (size_t)4 * E * 4;
    float* sH1 = (float*)p; p += (size_t)4 * E * 4;
    float* WcF = (float*)p; p += (size_t)4 * E * E * 4;  // 67 MB temp
    float* woutT = (float*)p; p += (size_t)E * 128 * 4;
    float* bcomb = (float*)p; p += (size_t)4 * E * 4;
    float* bias1 = (float*)p; p += (size_t)4 * E * 4;
    float* h0buf = (float*)p; p += (size_t)2 * E * 4;
    float* h1hist = (float*)p; p += (size_t)T_STEPS * E * 4;
    u32* bar = (u32*)p;       p += 1056 * 4;

    k_wcomb<<<dim3(8, 1024), 256, 0, stream>>>(wih0, wout, WcF);
    k_quant<<<4 * E, 64, 0, stream>>>(WcF, Qc, sC);
    k_quant<<<4 * E, 64, 0, stream>>>(whh0, Qh0, sH0);
    k_quant<<<4 * E, 64, 0, stream>>>(wih1, Qi1, sI1);
    k_quant<<<4 * E, 64, 0, stream>>>(whh1, Qh1, sH1);
    k_transpose_wout<<<(E * 128 + 255) / 256, 256, 0, stream>>>(wout, woutT);
    k_bcomb<<<(4 * E + 255) / 256, 256, 0, stream>>>(wih0, bout, bih0, bhh0, bih1, bhh1,
                                                     bcomb, bias1);
    k_init<<<(E + 255) / 256, 256, 0, stream>>>(lat, h0buf, h1hist, bar);

    k_persist<<<NB, NT, 0, stream>>>((const u32*)Qc, sC, (const u32*)Qh0, sH0,
                                     (const u32*)Qi1, sI1, (const u32*)Qh1, sH1,
                                     bcomb, bias1, h0buf, h1hist, bar);

    k_out<<<T_STEPS, 128, 0, stream>>>(woutT, h1hist, bout, (float*)d_out);
}